// Round 20
// baseline (280.819 us; speedup 1.0000x reference)
//
#include <hip/hip_runtime.h>

typedef unsigned int   u32;
typedef unsigned short u16;
typedef __bf16 bf16x8 __attribute__((ext_vector_type(8)));
typedef float  f32x4  __attribute__((ext_vector_type(4)));

__device__ __forceinline__ u16 f2bf(float f) {
    u32 u = __builtin_bit_cast(u32, f);
    u += 0x7FFFu + ((u >> 16) & 1u);
    return (u16)(u >> 16);
}
// packed f32x2 -> bf16x2 (RNE), single instruction
__device__ __forceinline__ u32 cvtpk(float a, float b) {
    u32 r;
    asm("v_cvt_pk_bf16_f32 %0, %1, %2" : "=v"(r) : "v"(a), "v"(b));
    return r;
}
__device__ __forceinline__ bf16x8 ldfrag(const u16* p) {
    return __builtin_bit_cast(bf16x8, *reinterpret_cast<const uint4*>(p));
}

// bank-conflict swizzle on the 16B-chunk index (0..63): fold bits[5:3] into [2:0].
__device__ __forceinline__ u32 swz(u32 i) { return i ^ ((i >> 3) & 7u); }

// ---------------------------------------------------------------------------
// Fused Swin branch, R20: single-window 6-wave WG engineered for TWO
// co-resident UNSYNCHRONIZED WGs/CU (__launch_bounds__(384,4), cap 128).
// Third attempt at this config; fixes R14's measured spill causes:
//   - K no longer crosses the barrier in regs: dedicated kreg LDS region,
//     scattered pre-barrier in its own 8-accumulator pass (wave-private).
//   - Only vpk (16 regs) crosses the barrier; freed at TOP of phase 3
//     (V^T scatter into kreg right after ak reads -- K dead, in-order LDS).
//   - Per-pass reg peaks: q/k ~76, v ~72, P3 ~110, P4 ~80 (all <= 128).
// LDS (u16): [0,12288) yln 24 frag blocks (phase 3: wave w's blocks
// {s*6+w} = P(ks=1) staging -> attn_out = proj A-frags ks=w);
// [12288,24576) qreg (Q B-frags; P ks=0 staging after QK^T);
// [24576,36864) kreg (K^T A-frags; V^T A-frags after ak reads).
// Total ~75.8KB/WG -> 2 WGs = 151.6KB (pool proven >=112.6KB by R3).
// Two free-running WGs overlap one's HBM phases with the other's MFMA.
// ---------------------------------------------------------------------------
template<int SHIFT>
__global__ __launch_bounds__(384, 4) void swin_branch(
    const float* __restrict__ xin, float* __restrict__ xout,
    const float* __restrict__ ln_g, const float* __restrict__ ln_b,
    const u16*   __restrict__ wqkv_t,  // [576][192] bf16 (pre-transposed)
    const float* __restrict__ qkv_b,   // [576]
    const u16*   __restrict__ wproj_t, // [192][192] bf16 (pre-transposed)
    const float* __restrict__ proj_b)  // [192]
{
    __shared__ __align__(16) u16 smem[36864];
    __shared__ float red1[6][64];
    __shared__ float red2[6][64];
    constexpr u32 QOFF = 12288, KOFF = 24576;
    constexpr float QSC = 0.17677669529663689f * 1.4426950408889634f; // 1/sqrt(32)*log2(e)

    const int tid  = threadIdx.x;
    const int wid  = tid >> 6;              // wave == head
    const int lane = tid & 63;
    const int lr   = lane & 15;
    const int lg   = lane >> 4;
    const u32 lsw  = swz((u32)lane);

    const int Wid = blockIdx.x;             // b*256 + wy*16 + wx
    const int b   = Wid >> 8;
    const int wy  = (Wid >> 4) & 15;
    const int wx  = Wid & 15;

    // ---- Phase 1: gather window (rolled), LayerNorm -> yln (frag layout) ----
    {
        const int ty = lane >> 3, tx = lane & 7;
        const int shy = (wy*8 + ty + SHIFT) & 127;
        const int shx = (wx*8 + tx + SHIFT) & 127;
        const float* xp = xin + ((size_t)((b*128 + shy)*128 + shx))*192 + wid*32;
        float xv[32];
        float s1 = 0.f, s2 = 0.f;
        #pragma unroll
        for (int j = 0; j < 8; ++j) {
            float4 v = reinterpret_cast<const float4*>(xp)[j];
            xv[j*4+0]=v.x; xv[j*4+1]=v.y; xv[j*4+2]=v.z; xv[j*4+3]=v.w;
            s1 += v.x+v.y+v.z+v.w;
            s2 += v.x*v.x + v.y*v.y + v.z*v.z + v.w*v.w;
        }
        red1[wid][lane] = s1; red2[wid][lane] = s2;
        __syncthreads();
        float a1 = 0.f, a2 = 0.f;
        #pragma unroll
        for (int w = 0; w < 6; ++w) { a1 += red1[w][lane]; a2 += red2[w][lane]; }
        const float mu = a1 * (1.f/192.f);
        const float rs = rsqrtf(a2 * (1.f/192.f) - mu*mu + 1e-5f);
        const float* gp = ln_g + wid*32;
        const float* bp = ln_b + wid*32;
        const u32 yblk = (u32)((lg*6 + wid)*512);
        #pragma unroll
        for (int cc8 = 0; cc8 < 4; ++cc8) {
            u32 pk[4];
            #pragma unroll
            for (int q = 0; q < 4; ++q) {
                int j = cc8*8 + q*2;
                float y0 = (xv[j]   - mu)*rs*gp[j]   + bp[j];
                float y1 = (xv[j+1] - mu)*rs*gp[j+1] + bp[j+1];
                pk[q] = cvtpk(y0, y1);
            }
            *reinterpret_cast<uint4*>(&smem[yblk + swz((u32)(lr + 16*cc8))*8]) =
                make_uint4(pk[0],pk[1],pk[2],pk[3]);
        }
    }
    __syncthreads();

    // ---- Phase 2: QKV GEMM, three 8-accumulator passes (reg cap 128) ----
    uint2 vpk[4][2];     // ONLY state crossing the barrier in regs
    {
        // pass q (SWAPPED): Q^T = mfma(Wq, yln) -> qreg as B-frag
        {
            f32x4 acc[4][2];
            #pragma unroll
            for (int mi=0; mi<4; ++mi)
                #pragma unroll
                for (int t=0; t<2; ++t) acc[mi][t] = f32x4{0.f,0.f,0.f,0.f};
            #pragma unroll
            for (int ks=0; ks<6; ++ks) {
                bf16x8 af[4];
                #pragma unroll
                for (int mi=0; mi<4; ++mi)
                    af[mi] = ldfrag(&smem[(u32)((mi*6+ks)*512) + lsw*8]);
                bf16x8 bw[2];
                #pragma unroll
                for (int t=0; t<2; ++t)
                    bw[t] = ldfrag(&wqkv_t[(wid*32 + t*16 + lr)*192 + 32*ks + 8*lg]);
                __builtin_amdgcn_s_setprio(1);
                #pragma unroll
                for (int mi=0; mi<4; ++mi)
                    #pragma unroll
                    for (int t=0; t<2; ++t)
                        acc[mi][t] = __builtin_amdgcn_mfma_f32_16x16x32_bf16(bw[t], af[mi], acc[mi][t], 0,0,0);
                __builtin_amdgcn_s_setprio(0);
            }
            #pragma unroll
            for (int t=0; t<2; ++t) {
                const float4 b4 = *reinterpret_cast<const float4*>(&qkv_b[wid*32 + t*16 + 4*lg]);
                const u32 chunk = (u32)lr + 16u*(u32)(2*t + (lg>>1));
                #pragma unroll
                for (int mi=0; mi<4; ++mi) {
                    float v0 = (acc[mi][t][0] + b4.x) * QSC;
                    float v1 = (acc[mi][t][1] + b4.y) * QSC;
                    float v2 = (acc[mi][t][2] + b4.z) * QSC;
                    float v3 = (acc[mi][t][3] + b4.w) * QSC;
                    *reinterpret_cast<uint2*>(
                        &smem[QOFF + (u32)(wid*2048) + mi*512 + swz(chunk)*8 + 4*(lg&1)]) =
                        make_uint2(cvtpk(v0,v1), cvtpk(v2,v3));
                }
            }
        }
        // pass k (SWAPPED): K^T = mfma(Wk, yln) -> kreg as A-frag (pre-barrier,
        // wave-private; chunk formula identical to R12's K scatter)
        {
            f32x4 acc[4][2];
            #pragma unroll
            for (int mi=0; mi<4; ++mi)
                #pragma unroll
                for (int t=0; t<2; ++t) acc[mi][t] = f32x4{0.f,0.f,0.f,0.f};
            #pragma unroll
            for (int ks=0; ks<6; ++ks) {
                bf16x8 af[4];
                #pragma unroll
                for (int mi=0; mi<4; ++mi)
                    af[mi] = ldfrag(&smem[(u32)((mi*6+ks)*512) + lsw*8]);
                bf16x8 bw[2];
                #pragma unroll
                for (int t=0; t<2; ++t)
                    bw[t] = ldfrag(&wqkv_t[(192 + wid*32 + t*16 + lr)*192 + 32*ks + 8*lg]);
                __builtin_amdgcn_s_setprio(1);
                #pragma unroll
                for (int mi=0; mi<4; ++mi)
                    #pragma unroll
                    for (int t=0; t<2; ++t)
                        acc[mi][t] = __builtin_amdgcn_mfma_f32_16x16x32_bf16(bw[t], af[mi], acc[mi][t], 0,0,0);
                __builtin_amdgcn_s_setprio(0);
            }
            #pragma unroll
            for (int t2=0; t2<2; ++t2) {
                const float4 b4 = *reinterpret_cast<const float4*>(&qkv_b[192 + wid*32 + t2*16 + 4*lg]);
                const u32 chunk = (u32)lr + 16u*(u32)(2*t2 + (lg>>1));
                #pragma unroll
                for (int mi=0; mi<4; ++mi)
                    *reinterpret_cast<uint2*>(
                        &smem[KOFF + (u32)(wid*2048) + mi*512 + swz(chunk)*8 + 4*(lg&1)]) =
                        make_uint2(cvtpk(acc[mi][t2][0] + b4.x, acc[mi][t2][1] + b4.y),
                                   cvtpk(acc[mi][t2][2] + b4.z, acc[mi][t2][3] + b4.w));
            }
        }
        // pass v (unswapped): V = mfma(yln, Wv) -> vpk regs
        {
            f32x4 acc[4][2];
            #pragma unroll
            for (int mi=0; mi<4; ++mi)
                #pragma unroll
                for (int t=0; t<2; ++t) acc[mi][t] = f32x4{0.f,0.f,0.f,0.f};
            #pragma unroll
            for (int ks=0; ks<6; ++ks) {
                bf16x8 af[4];
                #pragma unroll
                for (int mi=0; mi<4; ++mi)
                    af[mi] = ldfrag(&smem[(u32)((mi*6+ks)*512) + lsw*8]);
                bf16x8 bw[2];
                #pragma unroll
                for (int t=0; t<2; ++t)
                    bw[t] = ldfrag(&wqkv_t[(384 + wid*32 + t*16 + lr)*192 + 32*ks + 8*lg]);
                __builtin_amdgcn_s_setprio(1);
                #pragma unroll
                for (int mi=0; mi<4; ++mi)
                    #pragma unroll
                    for (int t=0; t<2; ++t)
                        acc[mi][t] = __builtin_amdgcn_mfma_f32_16x16x32_bf16(af[mi], bw[t], acc[mi][t], 0,0,0);
                __builtin_amdgcn_s_setprio(0);
            }
            #pragma unroll
            for (int tv=0; tv<2; ++tv) {
                const float bias = qkv_b[384 + wid*32 + tv*16 + lr];
                #pragma unroll
                for (int mi=0; mi<4; ++mi)
                    vpk[mi][tv] = make_uint2(
                        cvtpk(acc[mi][tv][0] + bias, acc[mi][tv][1] + bias),
                        cvtpk(acc[mi][tv][2] + bias, acc[mi][tv][3] + bias));
            }
        }
    }
    __syncthreads();   // yln reads done -> wave w's blocks {s*6+w} become scratch

    // ---- Phase 3: attention (all-swapped, wave-local) ----
    float rsum[4];       // per q-col tile nq (q is lane-local on lr)
    f32x4 o_[2][4];      // O^T [dv][nq]
    {
        const u32 W  = (u32)(wid*512);
        const u32 QB = QOFF + (u32)(wid*2048);
        const u32 KB = KOFF + (u32)(wid*2048);
        #define BLK(s) ((u32)(s)*3072u + W)

        // frag reads first (no outstanding writes on QB/KB -> immediate)
        bf16x8 bq[4], ak[4];
        #pragma unroll
        for (int nq=0; nq<4; ++nq) bq[nq] = ldfrag(&smem[QB + nq*512 + lsw*8]);
        #pragma unroll
        for (int mi=0; mi<4; ++mi) ak[mi] = ldfrag(&smem[KB + mi*512 + lsw*8]);
        __builtin_amdgcn_sched_barrier(0);

        // V^T scatter into kreg (K dead after ak reads; in-order wave-local
        // LDS) -- frees vpk at the top of the phase
        #pragma unroll
        for (int mi=0; mi<4; ++mi) {
            const u32 chunk = (u32)lr + 16u*(u32)(2*(mi&1) + (lg>>1));
            #pragma unroll
            for (int tv=0; tv<2; ++tv)
                *reinterpret_cast<uint2*>(
                    &smem[KB + (u32)((2*tv + (mi>>1))*512) + swz(chunk)*8 + 4*(lg&1)]) = vpk[mi][tv];
        }

        // q-col classes (per nq; col qt = 16nq+lr)
        int qcl[4];
        if constexpr (SHIFT > 0) {
            #pragma unroll
            for (int nq=0; nq<4; ++nq) {
                const int qt = 16*nq + lr;
                const int hu = wy*8 + (qt>>3);
                const int wu = wx*8 + (qt&7);
                qcl[nq] = ((hu >= 124) ? 2 : (hu >= 120 ? 1 : 0))*3
                        + ((wu >= 124) ? 2 : (wu >= 120 ? 1 : 0));
            }
        }

        // S^T = mfma(K,Q); exp2; zero-mask; pack; P scatter interleaved per mi
        #pragma unroll
        for (int mi=0; mi<4; ++mi) {
            f32x4 sr[4];
            __builtin_amdgcn_s_setprio(1);
            #pragma unroll
            for (int nq=0; nq<4; ++nq)
                sr[nq] = __builtin_amdgcn_mfma_f32_16x16x32_bf16(ak[mi], bq[nq],
                             f32x4{0.f,0.f,0.f,0.f}, 0,0,0);
            __builtin_amdgcn_s_setprio(0);
            #pragma unroll
            for (int rg=0; rg<4; ++rg) {
                int kcl = 0;
                if constexpr (SHIFT > 0) {
                    const int kt = 16*mi + 4*lg + rg;
                    const int hu = wy*8 + (kt>>3);
                    const int wu = wx*8 + (kt&7);
                    kcl = ((hu >= 124) ? 2 : (hu >= 120 ? 1 : 0))*3
                        + ((wu >= 124) ? 2 : (wu >= 120 ? 1 : 0));
                }
                #pragma unroll
                for (int nq=0; nq<4; ++nq) {
                    float e = exp2f(sr[nq][rg]);
                    if constexpr (SHIFT > 0)
                        e = (kcl == qcl[nq]) ? e : 0.f;
                    sr[nq][rg] = e;
                }
            }
            // P^T scatter (B-frag): ks0 -> QB(nq) (q dead), ks1 -> BLK(nq)
            const u32 chunk = (u32)lr + 16u*(u32)(2*(mi&1) + (lg>>1));
            #pragma unroll
            for (int nq=0; nq<4; ++nq) {
                const u32 base = (mi >> 1) ? BLK(nq) : (QB + nq*512);
                *reinterpret_cast<uint2*>(&smem[base + swz(chunk)*8 + 4*(lg&1)]) =
                    make_uint2(cvtpk(sr[nq][0], sr[nq][1]),
                               cvtpk(sr[nq][2], sr[nq][3]));
            }
        }
        __builtin_amdgcn_sched_barrier(0);

        bf16x8 bp[4][2];
        #pragma unroll
        for (int nq=0; nq<4; ++nq) {
            bp[nq][0] = ldfrag(&smem[QB + nq*512 + lsw*8]);
            bp[nq][1] = ldfrag(&smem[BLK(nq) + lsw*8]);
        }
        __builtin_amdgcn_sched_barrier(0);

        // row sums per q-col via ones-MFMA on P^T B-frags
        bf16x8 aones;
        {
            const u32 one2 = 0x3F803F80u;
            aones = __builtin_bit_cast(bf16x8, make_uint4(one2, one2, one2, one2));
        }
        #pragma unroll
        for (int nq=0; nq<4; ++nq) {
            f32x4 racc = __builtin_amdgcn_mfma_f32_16x16x32_bf16(aones, bp[nq][0],
                             f32x4{0.f,0.f,0.f,0.f}, 0,0,0);
            racc = __builtin_amdgcn_mfma_f32_16x16x32_bf16(aones, bp[nq][1], racc, 0,0,0);
            rsum[nq] = __builtin_amdgcn_rcpf(racc[0]);
        }

        bf16x8 av[2][2];
        #pragma unroll
        for (int dv=0; dv<2; ++dv)
            #pragma unroll
            for (int ks=0; ks<2; ++ks)
                av[dv][ks] = ldfrag(&smem[KB + (u32)((2*dv + ks)*512) + lsw*8]);
        __builtin_amdgcn_sched_barrier(0);

        // O^T = V^T * P^T
        __builtin_amdgcn_s_setprio(1);
        #pragma unroll
        for (int dv=0; dv<2; ++dv)
            #pragma unroll
            for (int nq=0; nq<4; ++nq) {
                o_[dv][nq] = __builtin_amdgcn_mfma_f32_16x16x32_bf16(av[dv][0], bp[nq][0],
                                 f32x4{0.f,0.f,0.f,0.f}, 0,0,0);
                o_[dv][nq] = __builtin_amdgcn_mfma_f32_16x16x32_bf16(av[dv][1], bp[nq][1],
                                 o_[dv][nq], 0,0,0);
            }
        __builtin_amdgcn_s_setprio(0);
        __builtin_amdgcn_sched_barrier(0);

        // normalized attn_out -> proj A-frag blocks BLK(nq) (uint2 writes)
        #pragma unroll
        for (int dv=0; dv<2; ++dv) {
            const u32 chunk = (u32)lr + 16u*(u32)(2*dv + (lg>>1));
            #pragma unroll
            for (int nq=0; nq<4; ++nq) {
                const float r = rsum[nq];
                *reinterpret_cast<uint2*>(&smem[BLK(nq) + swz(chunk)*8 + 4*(lg&1)]) =
                    make_uint2(cvtpk(o_[dv][nq][0]*r, o_[dv][nq][1]*r),
                               cvtpk(o_[dv][nq][2]*r, o_[dv][nq][3]*r));
            }
        }
        #undef BLK
    }
    __syncthreads();

    // ---- Phase 4: proj GEMM [64x192]@[192x192] + bias + residual ----
    {
        f32x4 a2[4][2];
        #pragma unroll
        for (int mi=0; mi<4; ++mi)
            #pragma unroll
            for (int ni=0; ni<2; ++ni) a2[mi][ni] = f32x4{0.f,0.f,0.f,0.f};
        #pragma unroll
        for (int ks=0; ks<6; ++ks) {
            bf16x8 af[4], bw[2];
            #pragma unroll
            for (int mi=0; mi<4; ++mi)
                af[mi] = ldfrag(&smem[(u32)((mi*6+ks)*512) + lsw*8]);
            #pragma unroll
            for (int ni=0; ni<2; ++ni)
                bw[ni] = ldfrag(&wproj_t[(wid*32 + 16*ni + lr)*192 + 32*ks + 8*lg]);
            __builtin_amdgcn_s_setprio(1);
            #pragma unroll
            for (int mi=0; mi<4; ++mi)
                #pragma unroll
                for (int ni=0; ni<2; ++ni)
                    a2[mi][ni] = __builtin_amdgcn_mfma_f32_16x16x32_bf16(af[mi], bw[ni], a2[mi][ni], 0,0,0);
            __builtin_amdgcn_s_setprio(0);
        }
        #pragma unroll
        for (int ni=0; ni<2; ++ni) {
            const int c  = wid*32 + 16*ni + lr;
            const float pb = proj_b[c];
            #pragma unroll
            for (int mi=0; mi<4; ++mi)
                #pragma unroll
                for (int rg=0; rg<4; ++rg) {
                    const int row = 16*mi + 4*lg + rg;
                    const int ty = row >> 3, tx = row & 7;
                    const int shy = (wy*8 + ty + SHIFT) & 127;
                    const int shx = (wx*8 + tx + SHIFT) & 127;
                    const size_t idx = ((size_t)((b*128 + shy)*128 + shx))*192 + c;
                    xout[idx] = xin[idx] + a2[mi][ni][rg] + pb;
                }
        }
    }
}

// ws layout (u16): [0) wqkv1_t 110592 | 110592) wproj1_t 36864 | 147456) wqkv2_t 110592 | 258048) wproj2_t 36864
__global__ void prep_weights(const float* __restrict__ qkv1, const float* __restrict__ proj1,
                             const float* __restrict__ qkv2, const float* __restrict__ proj2,
                             u16* __restrict__ ws)
{
    const int i = blockIdx.x*blockDim.x + threadIdx.x;
    if (i < 110592) {
        const int n = i / 192, k = i - n*192;
        ws[i]          = f2bf(qkv1[k*576 + n]);
        ws[147456 + i] = f2bf(qkv2[k*576 + n]);
    }
    if (i < 36864) {
        const int n = i / 192, k = i - n*192;
        ws[110592 + i] = f2bf(proj1[k*192 + n]);
        ws[258048 + i] = f2bf(proj2[k*192 + n]);
    }
}

extern "C" void kernel_launch(void* const* d_in, const int* in_sizes, int n_in,
                              void* d_out, int out_size, void* d_ws, size_t ws_size,
                              hipStream_t stream)
{
    const float* x       = (const float*)d_in[0];
    const float* ln1_g   = (const float*)d_in[1];
    const float* ln1_b   = (const float*)d_in[2];
    const float* qkv1_w  = (const float*)d_in[3];
    const float* qkv1_b  = (const float*)d_in[4];
    const float* proj1_w = (const float*)d_in[5];
    const float* proj1_b = (const float*)d_in[6];
    const float* ln2_g   = (const float*)d_in[7];
    const float* ln2_b   = (const float*)d_in[8];
    const float* qkv2_w  = (const float*)d_in[9];
    const float* qkv2_b  = (const float*)d_in[10];
    const float* proj2_w = (const float*)d_in[11];
    const float* proj2_b = (const float*)d_in[12];
    float* out = (float*)d_out;
    u16*   wsp = (u16*)d_ws;

    prep_weights<<<dim3(432), dim3(256), 0, stream>>>(qkv1_w, proj1_w, qkv2_w, proj2_w, wsp);
    swin_branch<0><<<dim3(2048), dim3(384), 0, stream>>>(x,   out, ln1_g, ln1_b,
                                                         wsp,        qkv1_b, wsp+110592, proj1_b);
    swin_branch<4><<<dim3(2048), dim3(384), 0, stream>>>(out, out, ln2_g, ln2_b,
                                                         wsp+147456, qkv2_b, wsp+258048, proj2_b);
}

// Round 21
// 256.681 us; speedup vs baseline: 1.0940x; 1.0940x over previous
//
#include <hip/hip_runtime.h>

typedef unsigned int   u32;
typedef unsigned short u16;
typedef __bf16 bf16x8 __attribute__((ext_vector_type(8)));
typedef float  f32x4  __attribute__((ext_vector_type(4)));

__device__ __forceinline__ u16 f2bf(float f) {
    u32 u = __builtin_bit_cast(u32, f);
    u += 0x7FFFu + ((u >> 16) & 1u);
    return (u16)(u >> 16);
}
// packed f32x2 -> bf16x2 (RNE), single instruction
__device__ __forceinline__ u32 cvtpk(float a, float b) {
    u32 r;
    asm("v_cvt_pk_bf16_f32 %0, %1, %2" : "=v"(r) : "v"(a), "v"(b));
    return r;
}
__device__ __forceinline__ bf16x8 ldfrag(const u16* p) {
    return __builtin_bit_cast(bf16x8, *reinterpret_cast<const uint4*>(p));
}

// bank-conflict swizzle on the 16B-chunk index (0..63): fold bits[5:3] into [2:0].
__device__ __forceinline__ u32 swz(u32 i) { return i ^ ((i >> 3) & 7u); }

// ---------------------------------------------------------------------------
// Fused Swin branch, R21: the 2-WGs/CU configuration with BOTH measured walls
// addressed by proven-safe budgets:
//   - regs: R20 proved the 3-pass QKV + swapped dataflow fits cap 128 with
//     NO spill (VGPR 68, FETCH clean). R21 adds only kpk (16 regs) crossing
//     the barrier; P3 uses R19's interleaved P staging (no p16 array).
//   - LDS: 52224 B/WG (yln 24KB + qreg 24KB + red 3KB); 2 WGs = 104.4KB <=
//     112.6KB PROVEN pool (R3). R20's 76.8KB/WG missed the pool (occ 17%).
// Two co-resident UNSYNCHRONIZED WGs finally overlap one WG's HBM phases
// with the other's MFMA phases -- the thing every barrier-locked scheme
// (R9/R13/R15) and phase-locked 12-wave WG could not do.
// LDS (u16): [0,12288) yln 24 frag blocks (phase 3: wave w's blocks {s*6+w}
// = K scratch -> P(ks=1) -> attn_out = proj A-frags ks=w);
// [12288,24576) qreg (Q B-frags -> P(ks=0) -> V^T).
// ---------------------------------------------------------------------------
template<int SHIFT>
__global__ __launch_bounds__(384, 4) void swin_branch(
    const float* __restrict__ xin, float* __restrict__ xout,
    const float* __restrict__ ln_g, const float* __restrict__ ln_b,
    const u16*   __restrict__ wqkv_t,  // [576][192] bf16 (pre-transposed)
    const float* __restrict__ qkv_b,   // [576]
    const u16*   __restrict__ wproj_t, // [192][192] bf16 (pre-transposed)
    const float* __restrict__ proj_b)  // [192]
{
    __shared__ __align__(16) u16 smem[24576];
    __shared__ float red1[6][64];
    __shared__ float red2[6][64];
    constexpr u32 QOFF = 12288;
    constexpr float QSC = 0.17677669529663689f * 1.4426950408889634f; // 1/sqrt(32)*log2(e)

    const int tid  = threadIdx.x;
    const int wid  = tid >> 6;              // wave == head
    const int lane = tid & 63;
    const int lr   = lane & 15;
    const int lg   = lane >> 4;
    const u32 lsw  = swz((u32)lane);

    const int Wid = blockIdx.x;             // b*256 + wy*16 + wx
    const int b   = Wid >> 8;
    const int wy  = (Wid >> 4) & 15;
    const int wx  = Wid & 15;

    // ---- Phase 1: gather window (rolled), LayerNorm -> yln (frag layout) ----
    {
        const int ty = lane >> 3, tx = lane & 7;
        const int shy = (wy*8 + ty + SHIFT) & 127;
        const int shx = (wx*8 + tx + SHIFT) & 127;
        const float* xp = xin + ((size_t)((b*128 + shy)*128 + shx))*192 + wid*32;
        float xv[32];
        float s1 = 0.f, s2 = 0.f;
        #pragma unroll
        for (int j = 0; j < 8; ++j) {
            float4 v = reinterpret_cast<const float4*>(xp)[j];
            xv[j*4+0]=v.x; xv[j*4+1]=v.y; xv[j*4+2]=v.z; xv[j*4+3]=v.w;
            s1 += v.x+v.y+v.z+v.w;
            s2 += v.x*v.x + v.y*v.y + v.z*v.z + v.w*v.w;
        }
        red1[wid][lane] = s1; red2[wid][lane] = s2;
        __syncthreads();
        float a1 = 0.f, a2 = 0.f;
        #pragma unroll
        for (int w = 0; w < 6; ++w) { a1 += red1[w][lane]; a2 += red2[w][lane]; }
        const float mu = a1 * (1.f/192.f);
        const float rs = rsqrtf(a2 * (1.f/192.f) - mu*mu + 1e-5f);
        const float* gp = ln_g + wid*32;
        const float* bp = ln_b + wid*32;
        const u32 yblk = (u32)((lg*6 + wid)*512);
        #pragma unroll
        for (int cc8 = 0; cc8 < 4; ++cc8) {
            u32 pk[4];
            #pragma unroll
            for (int q = 0; q < 4; ++q) {
                int j = cc8*8 + q*2;
                float y0 = (xv[j]   - mu)*rs*gp[j]   + bp[j];
                float y1 = (xv[j+1] - mu)*rs*gp[j+1] + bp[j+1];
                pk[q] = cvtpk(y0, y1);
            }
            *reinterpret_cast<uint4*>(&smem[yblk + swz((u32)(lr + 16*cc8))*8]) =
                make_uint4(pk[0],pk[1],pk[2],pk[3]);
        }
    }
    __syncthreads();

    // ---- Phase 2: QKV GEMM, three 8-accumulator passes (reg cap 128) ----
    uint2 kpk[4][2];     // K^T packed bf16 (crosses barrier in regs)
    uint2 vpk[4][2];     // V  packed bf16 (crosses barrier in regs)
    {
        // pass q (SWAPPED): Q^T = mfma(Wq, yln) -> qreg as B-frag
        {
            f32x4 acc[4][2];
            #pragma unroll
            for (int mi=0; mi<4; ++mi)
                #pragma unroll
                for (int t=0; t<2; ++t) acc[mi][t] = f32x4{0.f,0.f,0.f,0.f};
            #pragma unroll
            for (int ks=0; ks<6; ++ks) {
                bf16x8 af[4];
                #pragma unroll
                for (int mi=0; mi<4; ++mi)
                    af[mi] = ldfrag(&smem[(u32)((mi*6+ks)*512) + lsw*8]);
                bf16x8 bw[2];
                #pragma unroll
                for (int t=0; t<2; ++t)
                    bw[t] = ldfrag(&wqkv_t[(wid*32 + t*16 + lr)*192 + 32*ks + 8*lg]);
                __builtin_amdgcn_s_setprio(1);
                #pragma unroll
                for (int mi=0; mi<4; ++mi)
                    #pragma unroll
                    for (int t=0; t<2; ++t)
                        acc[mi][t] = __builtin_amdgcn_mfma_f32_16x16x32_bf16(bw[t], af[mi], acc[mi][t], 0,0,0);
                __builtin_amdgcn_s_setprio(0);
            }
            #pragma unroll
            for (int t=0; t<2; ++t) {
                const float4 b4 = *reinterpret_cast<const float4*>(&qkv_b[wid*32 + t*16 + 4*lg]);
                const u32 chunk = (u32)lr + 16u*(u32)(2*t + (lg>>1));
                #pragma unroll
                for (int mi=0; mi<4; ++mi) {
                    float v0 = (acc[mi][t][0] + b4.x) * QSC;
                    float v1 = (acc[mi][t][1] + b4.y) * QSC;
                    float v2 = (acc[mi][t][2] + b4.z) * QSC;
                    float v3 = (acc[mi][t][3] + b4.w) * QSC;
                    *reinterpret_cast<uint2*>(
                        &smem[QOFF + (u32)(wid*2048) + mi*512 + swz(chunk)*8 + 4*(lg&1)]) =
                        make_uint2(cvtpk(v0,v1), cvtpk(v2,v3));
                }
            }
        }
        // pass k (SWAPPED): K^T = mfma(Wk, yln) -> kpk regs
        {
            f32x4 acc[4][2];
            #pragma unroll
            for (int mi=0; mi<4; ++mi)
                #pragma unroll
                for (int t=0; t<2; ++t) acc[mi][t] = f32x4{0.f,0.f,0.f,0.f};
            #pragma unroll
            for (int ks=0; ks<6; ++ks) {
                bf16x8 af[4];
                #pragma unroll
                for (int mi=0; mi<4; ++mi)
                    af[mi] = ldfrag(&smem[(u32)((mi*6+ks)*512) + lsw*8]);
                bf16x8 bw[2];
                #pragma unroll
                for (int t=0; t<2; ++t)
                    bw[t] = ldfrag(&wqkv_t[(192 + wid*32 + t*16 + lr)*192 + 32*ks + 8*lg]);
                __builtin_amdgcn_s_setprio(1);
                #pragma unroll
                for (int mi=0; mi<4; ++mi)
                    #pragma unroll
                    for (int t=0; t<2; ++t)
                        acc[mi][t] = __builtin_amdgcn_mfma_f32_16x16x32_bf16(bw[t], af[mi], acc[mi][t], 0,0,0);
                __builtin_amdgcn_s_setprio(0);
            }
            #pragma unroll
            for (int t2=0; t2<2; ++t2) {
                const float4 b4 = *reinterpret_cast<const float4*>(&qkv_b[192 + wid*32 + t2*16 + 4*lg]);
                #pragma unroll
                for (int mi=0; mi<4; ++mi)
                    kpk[mi][t2] = make_uint2(
                        cvtpk(acc[mi][t2][0] + b4.x, acc[mi][t2][1] + b4.y),
                        cvtpk(acc[mi][t2][2] + b4.z, acc[mi][t2][3] + b4.w));
            }
        }
        // pass v (unswapped): V = mfma(yln, Wv) -> vpk regs
        {
            f32x4 acc[4][2];
            #pragma unroll
            for (int mi=0; mi<4; ++mi)
                #pragma unroll
                for (int t=0; t<2; ++t) acc[mi][t] = f32x4{0.f,0.f,0.f,0.f};
            #pragma unroll
            for (int ks=0; ks<6; ++ks) {
                bf16x8 af[4];
                #pragma unroll
                for (int mi=0; mi<4; ++mi)
                    af[mi] = ldfrag(&smem[(u32)((mi*6+ks)*512) + lsw*8]);
                bf16x8 bw[2];
                #pragma unroll
                for (int t=0; t<2; ++t)
                    bw[t] = ldfrag(&wqkv_t[(384 + wid*32 + t*16 + lr)*192 + 32*ks + 8*lg]);
                __builtin_amdgcn_s_setprio(1);
                #pragma unroll
                for (int mi=0; mi<4; ++mi)
                    #pragma unroll
                    for (int t=0; t<2; ++t)
                        acc[mi][t] = __builtin_amdgcn_mfma_f32_16x16x32_bf16(af[mi], bw[t], acc[mi][t], 0,0,0);
                __builtin_amdgcn_s_setprio(0);
            }
            #pragma unroll
            for (int tv=0; tv<2; ++tv) {
                const float bias = qkv_b[384 + wid*32 + tv*16 + lr];
                #pragma unroll
                for (int mi=0; mi<4; ++mi)
                    vpk[mi][tv] = make_uint2(
                        cvtpk(acc[mi][tv][0] + bias, acc[mi][tv][1] + bias),
                        cvtpk(acc[mi][tv][2] + bias, acc[mi][tv][3] + bias));
            }
        }
    }
    __syncthreads();   // yln reads done -> wave w's blocks {s*6+w} become scratch

    // ---- Phase 3: attention (R19's pipeline, wave-local) ----
    float rsum[4];       // per q-col tile nq (q is lane-local on lr)
    f32x4 o_[2][4];      // O^T [dv][nq]
    {
        const u32 W  = (u32)(wid*512);
        const u32 QB = QOFF + (u32)(wid*2048);
        #define BLK(s) ((u32)(s)*3072u + W)

        // bq reads FIRST (QB has no outstanding writes -> completes immediately)
        bf16x8 bq[4];
        #pragma unroll
        for (int nq=0; nq<4; ++nq) bq[nq] = ldfrag(&smem[QB + nq*512 + lsw*8]);

        // K scatter (A-frag) from kpk -> scratch blocks BLK(mi)
        #pragma unroll
        for (int t2=0; t2<2; ++t2) {
            const u32 chunk = (u32)lr + 16u*(u32)(2*t2 + (lg>>1));
            #pragma unroll
            for (int mi=0; mi<4; ++mi)
                *reinterpret_cast<uint2*>(
                    &smem[BLK(mi) + swz(chunk)*8 + 4*(lg&1)]) = kpk[mi][t2];
        }
        bf16x8 ak[4];
        #pragma unroll
        for (int mi=0; mi<4; ++mi) ak[mi] = ldfrag(&smem[BLK(mi) + lsw*8]);
        __builtin_amdgcn_sched_barrier(0);

        // q-col classes (per nq; col qt = 16nq+lr)
        int qcl[4];
        if constexpr (SHIFT > 0) {
            #pragma unroll
            for (int nq=0; nq<4; ++nq) {
                const int qt = 16*nq + lr;
                const int hu = wy*8 + (qt>>3);
                const int wu = wx*8 + (qt&7);
                qcl[nq] = ((hu >= 124) ? 2 : (hu >= 120 ? 1 : 0))*3
                        + ((wu >= 124) ? 2 : (wu >= 120 ? 1 : 0));
            }
        }

        // S^T = mfma(K,Q); exp2; zero-mask; pack; P scatter interleaved per mi
        #pragma unroll
        for (int mi=0; mi<4; ++mi) {
            f32x4 sr[4];
            __builtin_amdgcn_s_setprio(1);
            #pragma unroll
            for (int nq=0; nq<4; ++nq)
                sr[nq] = __builtin_amdgcn_mfma_f32_16x16x32_bf16(ak[mi], bq[nq],
                             f32x4{0.f,0.f,0.f,0.f}, 0,0,0);
            __builtin_amdgcn_s_setprio(0);
            #pragma unroll
            for (int rg=0; rg<4; ++rg) {
                int kcl = 0;
                if constexpr (SHIFT > 0) {
                    const int kt = 16*mi + 4*lg + rg;
                    const int hu = wy*8 + (kt>>3);
                    const int wu = wx*8 + (kt&7);
                    kcl = ((hu >= 124) ? 2 : (hu >= 120 ? 1 : 0))*3
                        + ((wu >= 124) ? 2 : (wu >= 120 ? 1 : 0));
                }
                #pragma unroll
                for (int nq=0; nq<4; ++nq) {
                    float e = exp2f(sr[nq][rg]);
                    if constexpr (SHIFT > 0)
                        e = (kcl == qcl[nq]) ? e : 0.f;
                    sr[nq][rg] = e;
                }
            }
            // P^T scatter (B-frag): ks0 -> QB(nq) (q dead), ks1 -> BLK(nq) (K dead)
            const u32 chunk = (u32)lr + 16u*(u32)(2*(mi&1) + (lg>>1));
            #pragma unroll
            for (int nq=0; nq<4; ++nq) {
                const u32 base = (mi >> 1) ? BLK(nq) : (QB + nq*512);
                *reinterpret_cast<uint2*>(&smem[base + swz(chunk)*8 + 4*(lg&1)]) =
                    make_uint2(cvtpk(sr[nq][0], sr[nq][1]),
                               cvtpk(sr[nq][2], sr[nq][3]));
            }
        }
        __builtin_amdgcn_sched_barrier(0);

        bf16x8 bp[4][2];
        #pragma unroll
        for (int nq=0; nq<4; ++nq) {
            bp[nq][0] = ldfrag(&smem[QB + nq*512 + lsw*8]);
            bp[nq][1] = ldfrag(&smem[BLK(nq) + lsw*8]);
        }

        // V^T scatter (A-frag) into QB blocks, after bp reads (in-order LDS;
        // the rsum MFMAs below cover the V-write latency before av reads)
        #pragma unroll
        for (int mi=0; mi<4; ++mi) {
            const u32 chunk = (u32)lr + 16u*(u32)(2*(mi&1) + (lg>>1));
            #pragma unroll
            for (int tv=0; tv<2; ++tv)
                *reinterpret_cast<uint2*>(
                    &smem[QB + (u32)((2*tv + (mi>>1))*512) + swz(chunk)*8 + 4*(lg&1)]) = vpk[mi][tv];
        }
        __builtin_amdgcn_sched_barrier(0);

        // row sums per q-col via ones-MFMA on P^T B-frags
        bf16x8 aones;
        {
            const u32 one2 = 0x3F803F80u;
            aones = __builtin_bit_cast(bf16x8, make_uint4(one2, one2, one2, one2));
        }
        #pragma unroll
        for (int nq=0; nq<4; ++nq) {
            f32x4 racc = __builtin_amdgcn_mfma_f32_16x16x32_bf16(aones, bp[nq][0],
                             f32x4{0.f,0.f,0.f,0.f}, 0,0,0);
            racc = __builtin_amdgcn_mfma_f32_16x16x32_bf16(aones, bp[nq][1], racc, 0,0,0);
            rsum[nq] = __builtin_amdgcn_rcpf(racc[0]);
        }

        bf16x8 av[2][2];
        #pragma unroll
        for (int dv=0; dv<2; ++dv)
            #pragma unroll
            for (int ks=0; ks<2; ++ks)
                av[dv][ks] = ldfrag(&smem[QB + (u32)((2*dv + ks)*512) + lsw*8]);
        __builtin_amdgcn_sched_barrier(0);

        // O^T = V^T * P^T
        __builtin_amdgcn_s_setprio(1);
        #pragma unroll
        for (int dv=0; dv<2; ++dv)
            #pragma unroll
            for (int nq=0; nq<4; ++nq) {
                o_[dv][nq] = __builtin_amdgcn_mfma_f32_16x16x32_bf16(av[dv][0], bp[nq][0],
                                 f32x4{0.f,0.f,0.f,0.f}, 0,0,0);
                o_[dv][nq] = __builtin_amdgcn_mfma_f32_16x16x32_bf16(av[dv][1], bp[nq][1],
                                 o_[dv][nq], 0,0,0);
            }
        __builtin_amdgcn_s_setprio(0);
        __builtin_amdgcn_sched_barrier(0);

        // normalized attn_out -> proj A-frag blocks BLK(nq) (uint2 writes)
        #pragma unroll
        for (int dv=0; dv<2; ++dv) {
            const u32 chunk = (u32)lr + 16u*(u32)(2*dv + (lg>>1));
            #pragma unroll
            for (int nq=0; nq<4; ++nq) {
                const float r = rsum[nq];
                *reinterpret_cast<uint2*>(&smem[BLK(nq) + swz(chunk)*8 + 4*(lg&1)]) =
                    make_uint2(cvtpk(o_[dv][nq][0]*r, o_[dv][nq][1]*r),
                               cvtpk(o_[dv][nq][2]*r, o_[dv][nq][3]*r));
            }
        }
        #undef BLK
    }
    __syncthreads();

    // ---- Phase 4: proj GEMM [64x192]@[192x192] + bias + residual ----
    {
        f32x4 a2[4][2];
        #pragma unroll
        for (int mi=0; mi<4; ++mi)
            #pragma unroll
            for (int ni=0; ni<2; ++ni) a2[mi][ni] = f32x4{0.f,0.f,0.f,0.f};
        #pragma unroll
        for (int ks=0; ks<6; ++ks) {
            bf16x8 af[4], bw[2];
            #pragma unroll
            for (int mi=0; mi<4; ++mi)
                af[mi] = ldfrag(&smem[(u32)((mi*6+ks)*512) + lsw*8]);
            #pragma unroll
            for (int ni=0; ni<2; ++ni)
                bw[ni] = ldfrag(&wproj_t[(wid*32 + 16*ni + lr)*192 + 32*ks + 8*lg]);
            __builtin_amdgcn_s_setprio(1);
            #pragma unroll
            for (int mi=0; mi<4; ++mi)
                #pragma unroll
                for (int ni=0; ni<2; ++ni)
                    a2[mi][ni] = __builtin_amdgcn_mfma_f32_16x16x32_bf16(af[mi], bw[ni], a2[mi][ni], 0,0,0);
            __builtin_amdgcn_s_setprio(0);
        }
        #pragma unroll
        for (int ni=0; ni<2; ++ni) {
            const int c  = wid*32 + 16*ni + lr;
            const float pb = proj_b[c];
            #pragma unroll
            for (int mi=0; mi<4; ++mi)
                #pragma unroll
                for (int rg=0; rg<4; ++rg) {
                    const int row = 16*mi + 4*lg + rg;
                    const int ty = row >> 3, tx = row & 7;
                    const int shy = (wy*8 + ty + SHIFT) & 127;
                    const int shx = (wx*8 + tx + SHIFT) & 127;
                    const size_t idx = ((size_t)((b*128 + shy)*128 + shx))*192 + c;
                    xout[idx] = xin[idx] + a2[mi][ni][rg] + pb;
                }
        }
    }
}

// ws layout (u16): [0) wqkv1_t 110592 | 110592) wproj1_t 36864 | 147456) wqkv2_t 110592 | 258048) wproj2_t 36864
__global__ void prep_weights(const float* __restrict__ qkv1, const float* __restrict__ proj1,
                             const float* __restrict__ qkv2, const float* __restrict__ proj2,
                             u16* __restrict__ ws)
{
    const int i = blockIdx.x*blockDim.x + threadIdx.x;
    if (i < 110592) {
        const int n = i / 192, k = i - n*192;
        ws[i]          = f2bf(qkv1[k*576 + n]);
        ws[147456 + i] = f2bf(qkv2[k*576 + n]);
    }
    if (i < 36864) {
        const int n = i / 192, k = i - n*192;
        ws[110592 + i] = f2bf(proj1[k*192 + n]);
        ws[258048 + i] = f2bf(proj2[k*192 + n]);
    }
}

extern "C" void kernel_launch(void* const* d_in, const int* in_sizes, int n_in,
                              void* d_out, int out_size, void* d_ws, size_t ws_size,
                              hipStream_t stream)
{
    const float* x       = (const float*)d_in[0];
    const float* ln1_g   = (const float*)d_in[1];
    const float* ln1_b   = (const float*)d_in[2];
    const float* qkv1_w  = (const float*)d_in[3];
    const float* qkv1_b  = (const float*)d_in[4];
    const float* proj1_w = (const float*)d_in[5];
    const float* proj1_b = (const float*)d_in[6];
    const float* ln2_g   = (const float*)d_in[7];
    const float* ln2_b   = (const float*)d_in[8];
    const float* qkv2_w  = (const float*)d_in[9];
    const float* qkv2_b  = (const float*)d_in[10];
    const float* proj2_w = (const float*)d_in[11];
    const float* proj2_b = (const float*)d_in[12];
    float* out = (float*)d_out;
    u16*   wsp = (u16*)d_ws;

    prep_weights<<<dim3(432), dim3(256), 0, stream>>>(qkv1_w, proj1_w, qkv2_w, proj2_w, wsp);
    swin_branch<0><<<dim3(2048), dim3(384), 0, stream>>>(x,   out, ln1_g, ln1_b,
                                                         wsp,        qkv1_b, wsp+110592, proj1_b);
    swin_branch<4><<<dim3(2048), dim3(384), 0, stream>>>(out, out, ln2_g, ln2_b,
                                                         wsp+147456, qkv2_b, wsp+258048, proj2_b);
}